// Round 6
// baseline (892.264 us; speedup 1.0000x reference)
//
#include <hip/hip_runtime.h>
#include <hip/hip_bf16.h>

namespace {

constexpr int HD = 128;   // H
constexpr int SB = 1024;  // S
constexpr int BB = 1024;  // B

typedef __attribute__((ext_vector_type(4)))  float          f32x4;
typedef __attribute__((ext_vector_type(16))) float          f32x16;
typedef __attribute__((ext_vector_type(8)))  __bf16         bf16x8;
typedef __attribute__((ext_vector_type(8)))  unsigned short u16x8;
typedef __attribute__((ext_vector_type(4)))  unsigned short u16x4;

__device__ __forceinline__ float fast_tanh(float x) {
  float e = __expf(2.0f * x);
  return 1.0f - 2.0f * __builtin_amdgcn_rcpf(e + 1.0f);
}

} // namespace

// One block per batch row b. 8 waves. Wave w, chunk c computes scores for
// s in [c*256 + w*32, +32) over all 128 o's, via 32x32x16 bf16 MFMA with
// hi/lo split (3 products) for ~fp32 accuracy. Then block softmax over S.
extern "C" __global__ __launch_bounds__(512, 2)
void attn_fused(const float* __restrict__ hidden,
                const float* __restrict__ enc,
                const float* __restrict__ W,
                const float* __restrict__ bias,
                const float* __restrict__ vvec,
                float* __restrict__ out)
{
  __shared__ unsigned short WeHi[HD * HD];  // 32 KB, swizzled row-major bf16
  __shared__ unsigned short WeLo[HD * HD];  // 32 KB
  __shared__ float hid[HD];
  __shared__ float ehb[HD];                 // eh[b,o] + bias[o]
  __shared__ float sc[SB];                  // scores
  __shared__ float red[16];

  const int b    = blockIdx.x;
  const int tid  = threadIdx.x;
  const int lane = tid & 63;
  const int wv   = tid >> 6;   // wave 0..7
  const int l31  = lane & 31;
  const int hi   = lane >> 5;  // 0/1

  if (tid < 32)
    ((f32x4*)hid)[tid] = ((const f32x4*)(hidden + (size_t)b * HD))[tid];
  __syncthreads();

  if (tid < HD) {
    // ehb[o] = bias[o] + sum_h hidden[b,h] * W[o,h]   (Wh part, fp32)
    const float* wr = W + (size_t)tid * (2 * HD);
    float acc = bias[tid];
    #pragma unroll
    for (int h = 0; h < HD; h += 4) {
      f32x4 wq = *(const f32x4*)(wr + h);
      acc += hid[h]     * wq[0];
      acc += hid[h + 1] * wq[1];
      acc += hid[h + 2] * wq[2];
      acc += hid[h + 3] * wq[3];
    }
    ehb[tid] = acc;
  } else {
    // We[o,h] = W[o, 128+h] -> bf16 hi/lo into LDS, XOR-swizzled 16B granules
    for (int e = tid - HD; e < (HD * HD / 4); e += 384) {
      const int o  = e >> 5;
      const int h4 = (e & 31) << 2;
      f32x4 x = *(const f32x4*)(W + (size_t)o * (2 * HD) + HD + h4);
      const int g   = (h4 >> 3) ^ (o & 15);
      const int idx = o * HD + g * 8 + (h4 & 7);
      u16x4 hv, lv;
      #pragma unroll
      for (int j = 0; j < 4; ++j) {
        float xx = x[j];
        __bf16 hb = (__bf16)xx;
        float hf = (float)hb;
        __bf16 lb = (__bf16)(xx - hf);
        hv[j] = __builtin_bit_cast(unsigned short, hb);
        lv[j] = __builtin_bit_cast(unsigned short, lb);
      }
      *(u16x4*)&WeHi[idx] = hv;
      *(u16x4*)&WeLo[idx] = lv;
    }
  }
  __syncthreads();

  // per-lane o-constants: o = t*32 + l31 for 4 o-tiles
  const float vt0 = vvec[l31],      vt1 = vvec[32 + l31];
  const float vt2 = vvec[64 + l31], vt3 = vvec[96 + l31];
  const float et0 = ehb[l31],       et1 = ehb[32 + l31];
  const float et2 = ehb[64 + l31],  et3 = ehb[96 + l31];

  for (int c = 0; c < 4; ++c) {
    const int s0 = c * 256 + wv * 32;
    // A-fragment source: enc[b, s0+l31, k], k = ks*16 + hi*8 + 0..7
    const float* ap = enc + ((size_t)b * SB + (s0 + l31)) * HD + hi * 8;

    // preload the whole K=128 strip (8 frags of 8 f32) -> loads stay in flight
    f32x4 araw[16];
    #pragma unroll
    for (int ks = 0; ks < 8; ++ks) {
      araw[2 * ks]     = *(const f32x4*)(ap + ks * 16);
      araw[2 * ks + 1] = *(const f32x4*)(ap + ks * 16 + 4);
    }

    f32x16 acc0 = {}, acc1 = {}, acc2 = {}, acc3 = {};

    #pragma unroll
    for (int ks = 0; ks < 8; ++ks) {
      bf16x8 ah, al;
      #pragma unroll
      for (int j = 0; j < 8; ++j) {
        float xx = (j < 4) ? araw[2 * ks][j] : araw[2 * ks + 1][j - 4];
        __bf16 hb = (__bf16)xx;
        ah[j] = hb;
        al[j] = (__bf16)(xx - (float)hb);
      }
      const int gsw = ((ks * 2 + hi) ^ (l31 & 15)) * 8;

#define DO_TILE(ACC, T)                                                      \
      {                                                                      \
        const int bi = ((T) * 32 + l31) * HD + gsw;                          \
        bf16x8 bh = __builtin_bit_cast(bf16x8, *(const u16x8*)&WeHi[bi]);    \
        bf16x8 bl = __builtin_bit_cast(bf16x8, *(const u16x8*)&WeLo[bi]);    \
        ACC = __builtin_amdgcn_mfma_f32_32x32x16_bf16(ah, bh, ACC, 0, 0, 0); \
        ACC = __builtin_amdgcn_mfma_f32_32x32x16_bf16(al, bh, ACC, 0, 0, 0); \
        ACC = __builtin_amdgcn_mfma_f32_32x32x16_bf16(ah, bl, ACC, 0, 0, 0); \
      }

      DO_TILE(acc0, 0)
      DO_TILE(acc1, 1)
      DO_TILE(acc2, 2)
      DO_TILE(acc3, 3)
#undef DO_TILE
    }

    // epilogue: ps[r] = sum_o v[o]*tanh(ehb[o] + ee[s,o]); o = lane&31 per tile
    float ps[16];
    #pragma unroll
    for (int r = 0; r < 16; ++r) {
      ps[r] = vt0 * fast_tanh(acc0[r] + et0)
            + vt1 * fast_tanh(acc1[r] + et1)
            + vt2 * fast_tanh(acc2[r] + et2)
            + vt3 * fast_tanh(acc3[r] + et3);
    }
    // reduce over the 32 o-lanes (stays within each 32-lane half)
    #pragma unroll
    for (int d = 1; d <= 16; d <<= 1) {
      #pragma unroll
      for (int r = 0; r < 16; ++r)
        ps[r] += __shfl_xor(ps[r], d, 64);
    }
    if (l31 == 0) {
      #pragma unroll
      for (int r = 0; r < 16; ++r) {
        const int row = (r & 3) + 8 * (r >> 2) + 4 * hi;  // C/D row map
        sc[s0 + row] = ps[r];
      }
    }
  }
  __syncthreads();

  // ---- softmax over S = 1024 ----
  const float x0 = sc[tid];
  const float x1 = sc[tid + 512];
  float m = fmaxf(x0, x1);
  #pragma unroll
  for (int d = 32; d >= 1; d >>= 1) m = fmaxf(m, __shfl_xor(m, d, 64));
  if (lane == 0) red[wv] = m;
  __syncthreads();
  float M = red[0];
  #pragma unroll
  for (int i = 1; i < 8; ++i) M = fmaxf(M, red[i]);
  const float e0 = __expf(x0 - M);
  const float e1 = __expf(x1 - M);
  float s2 = e0 + e1;
  #pragma unroll
  for (int d = 32; d >= 1; d >>= 1) s2 += __shfl_xor(s2, d, 64);
  if (lane == 0) red[8 + wv] = s2;
  __syncthreads();
  float T = 0.0f;
  #pragma unroll
  for (int i = 0; i < 8; ++i) T += red[8 + i];
  const float inv = 1.0f / T;
  out[(size_t)b * SB + tid]       = e0 * inv;
  out[(size_t)b * SB + 512 + tid] = e1 * inv;
}

extern "C" void kernel_launch(void* const* d_in, const int* in_sizes, int n_in,
                              void* d_out, int out_size, void* d_ws, size_t ws_size,
                              hipStream_t stream) {
  const float* hidden = (const float*)d_in[0];
  const float* enc    = (const float*)d_in[1];
  const float* W      = (const float*)d_in[2];
  const float* bias   = (const float*)d_in[3];
  const float* vvec   = (const float*)d_in[4];
  float* out = (float*)d_out;
  (void)in_sizes; (void)n_in; (void)out_size; (void)d_ws; (void)ws_size;
  attn_fused<<<dim3(BB), dim3(512), 0, stream>>>(hidden, enc, W, bias, vvec, out);
}

// Round 10
// 890.374 us; speedup vs baseline: 1.0021x; 1.0021x over previous
//
#include <hip/hip_runtime.h>
#include <hip/hip_bf16.h>

namespace {

constexpr int HD = 128;   // H
constexpr int SB = 1024;  // S
constexpr int BB = 1024;  // B

typedef __attribute__((ext_vector_type(4)))  float          f32x4;
typedef __attribute__((ext_vector_type(16))) float          f32x16;
typedef __attribute__((ext_vector_type(8)))  __bf16         bf16x8;
typedef __attribute__((ext_vector_type(8)))  unsigned short u16x8;
typedef __attribute__((ext_vector_type(4)))  unsigned short u16x4;

__device__ __forceinline__ float fast_tanh(float x) {
  float e = __expf(2.0f * x);
  return 1.0f - 2.0f * __builtin_amdgcn_rcpf(e + 1.0f);
}

} // namespace

// One block per batch row b. 8 waves. Wave w, chunk c computes scores for
// s in [c*256 + w*32, +32) over all 128 o's, via 32x32x16 bf16 MFMA with
// hi/lo split (3 products) for ~fp32 accuracy. Then block softmax over S.
//
// __launch_bounds__(512, 1): hipcc treats arg2 as min BLOCKS/CU (CUDA
// semantics — measured R6: (512,2) gave VGPR_Count=128 + 227 MB of scratch
// spill writes). 1 block/CU -> 2 waves/SIMD -> 256-VGPR cap, no spill.
extern "C" __global__ __launch_bounds__(512, 1)
void attn_fused(const float* __restrict__ hidden,
                const float* __restrict__ enc,
                const float* __restrict__ W,
                const float* __restrict__ bias,
                const float* __restrict__ vvec,
                float* __restrict__ out)
{
  __shared__ unsigned short WeHi[HD * HD];  // 32 KB, swizzled row-major bf16
  __shared__ unsigned short WeLo[HD * HD];  // 32 KB
  __shared__ float hid[HD];
  __shared__ float ehb[HD];                 // eh[b,o] + bias[o]
  __shared__ float sc[SB];                  // scores
  __shared__ float red[16];

  const int b    = blockIdx.x;
  const int tid  = threadIdx.x;
  const int lane = tid & 63;
  const int wv   = tid >> 6;   // wave 0..7
  const int l31  = lane & 31;
  const int hi   = lane >> 5;  // 0/1

  if (tid < 32)
    ((f32x4*)hid)[tid] = ((const f32x4*)(hidden + (size_t)b * HD))[tid];
  __syncthreads();

  if (tid < HD) {
    // ehb[o] = bias[o] + sum_h hidden[b,h] * W[o,h]   (Wh part, fp32)
    const float* wr = W + (size_t)tid * (2 * HD);
    float acc = bias[tid];
    #pragma unroll
    for (int h = 0; h < HD; h += 4) {
      f32x4 wq = *(const f32x4*)(wr + h);
      acc += hid[h]     * wq[0];
      acc += hid[h + 1] * wq[1];
      acc += hid[h + 2] * wq[2];
      acc += hid[h + 3] * wq[3];
    }
    ehb[tid] = acc;
  } else {
    // We[o,h] = W[o, 128+h] -> bf16 hi/lo into LDS, XOR-swizzled 16B granules
    for (int e = tid - HD; e < (HD * HD / 4); e += 384) {
      const int o  = e >> 5;
      const int h4 = (e & 31) << 2;
      f32x4 x = *(const f32x4*)(W + (size_t)o * (2 * HD) + HD + h4);
      const int g   = (h4 >> 3) ^ (o & 15);
      const int idx = o * HD + g * 8 + (h4 & 7);
      u16x4 hv, lv;
      #pragma unroll
      for (int j = 0; j < 4; ++j) {
        float xx = x[j];
        __bf16 hb = (__bf16)xx;
        float hf = (float)hb;
        __bf16 lb = (__bf16)(xx - hf);
        hv[j] = __builtin_bit_cast(unsigned short, hb);
        lv[j] = __builtin_bit_cast(unsigned short, lb);
      }
      *(u16x4*)&WeHi[idx] = hv;
      *(u16x4*)&WeLo[idx] = lv;
    }
  }
  __syncthreads();

  // per-lane o-constants: o = t*32 + l31 for 4 o-tiles
  const float vt0 = vvec[l31],      vt1 = vvec[32 + l31];
  const float vt2 = vvec[64 + l31], vt3 = vvec[96 + l31];
  const float et0 = ehb[l31],       et1 = ehb[32 + l31];
  const float et2 = ehb[64 + l31],  et3 = ehb[96 + l31];

  for (int c = 0; c < 4; ++c) {
    const int s0 = c * 256 + wv * 32;
    // A-fragment source: enc[b, s0+l31, k], k = ks*16 + hi*8 + 0..7
    const float* ap = enc + ((size_t)b * SB + (s0 + l31)) * HD + hi * 8;

    // preload the whole K=128 strip (8 frags of 8 f32) -> loads stay in flight
    f32x4 araw[16];
    #pragma unroll
    for (int ks = 0; ks < 8; ++ks) {
      araw[2 * ks]     = *(const f32x4*)(ap + ks * 16);
      araw[2 * ks + 1] = *(const f32x4*)(ap + ks * 16 + 4);
    }

    f32x16 acc0 = {}, acc1 = {}, acc2 = {}, acc3 = {};

    #pragma unroll
    for (int ks = 0; ks < 8; ++ks) {
      bf16x8 ah, al;
      #pragma unroll
      for (int j = 0; j < 8; ++j) {
        float xx = (j < 4) ? araw[2 * ks][j] : araw[2 * ks + 1][j - 4];
        __bf16 hb = (__bf16)xx;
        ah[j] = hb;
        al[j] = (__bf16)(xx - (float)hb);
      }
      const int gsw = ((ks * 2 + hi) ^ (l31 & 15)) * 8;

#define DO_TILE(ACC, T)                                                      \
      {                                                                      \
        const int bi = ((T) * 32 + l31) * HD + gsw;                          \
        bf16x8 bh = __builtin_bit_cast(bf16x8, *(const u16x8*)&WeHi[bi]);    \
        bf16x8 bl = __builtin_bit_cast(bf16x8, *(const u16x8*)&WeLo[bi]);    \
        ACC = __builtin_amdgcn_mfma_f32_32x32x16_bf16(ah, bh, ACC, 0, 0, 0); \
        ACC = __builtin_amdgcn_mfma_f32_32x32x16_bf16(al, bh, ACC, 0, 0, 0); \
        ACC = __builtin_amdgcn_mfma_f32_32x32x16_bf16(ah, bl, ACC, 0, 0, 0); \
      }

      DO_TILE(acc0, 0)
      DO_TILE(acc1, 1)
      DO_TILE(acc2, 2)
      DO_TILE(acc3, 3)
#undef DO_TILE
    }

    // epilogue: ps[r] = sum_o v[o]*tanh(ehb[o] + ee[s,o]); o = lane&31 per tile
    float ps[16];
    #pragma unroll
    for (int r = 0; r < 16; ++r) {
      ps[r] = vt0 * fast_tanh(acc0[r] + et0)
            + vt1 * fast_tanh(acc1[r] + et1)
            + vt2 * fast_tanh(acc2[r] + et2)
            + vt3 * fast_tanh(acc3[r] + et3);
    }
    // reduce over the 32 o-lanes (stays within each 32-lane half)
    #pragma unroll
    for (int d = 1; d <= 16; d <<= 1) {
      #pragma unroll
      for (int r = 0; r < 16; ++r)
        ps[r] += __shfl_xor(ps[r], d, 64);
    }
    if (l31 == 0) {
      #pragma unroll
      for (int r = 0; r < 16; ++r) {
        const int row = (r & 3) + 8 * (r >> 2) + 4 * hi;  // C/D row map
        sc[s0 + row] = ps[r];
      }
    }
  }
  __syncthreads();

  // ---- softmax over S = 1024 ----
  const float x0 = sc[tid];
  const float x1 = sc[tid + 512];
  float m = fmaxf(x0, x1);
  #pragma unroll
  for (int d = 32; d >= 1; d >>= 1) m = fmaxf(m, __shfl_xor(m, d, 64));
  if (lane == 0) red[wv] = m;
  __syncthreads();
  float M = red[0];
  #pragma unroll
  for (int i = 1; i < 8; ++i) M = fmaxf(M, red[i]);
  const float e0 = __expf(x0 - M);
  const float e1 = __expf(x1 - M);
  float s2 = e0 + e1;
  #pragma unroll
  for (int d = 32; d >= 1; d >>= 1) s2 += __shfl_xor(s2, d, 64);
  if (lane == 0) red[8 + wv] = s2;
  __syncthreads();
  float T = 0.0f;
  #pragma unroll
  for (int i = 0; i < 8; ++i) T += red[8 + i];
  const float inv = 1.0f / T;
  out[(size_t)b * SB + tid]       = e0 * inv;
  out[(size_t)b * SB + 512 + tid] = e1 * inv;
}

extern "C" void kernel_launch(void* const* d_in, const int* in_sizes, int n_in,
                              void* d_out, int out_size, void* d_ws, size_t ws_size,
                              hipStream_t stream) {
  const float* hidden = (const float*)d_in[0];
  const float* enc    = (const float*)d_in[1];
  const float* W      = (const float*)d_in[2];
  const float* bias   = (const float*)d_in[3];
  const float* vvec   = (const float*)d_in[4];
  float* out = (float*)d_out;
  (void)in_sizes; (void)n_in; (void)out_size; (void)d_ws; (void)ws_size;
  attn_fused<<<dim3(BB), dim3(512), 0, stream>>>(hidden, enc, W, bias, vvec, out);
}

// Round 11
// 882.322 us; speedup vs baseline: 1.0113x; 1.0091x over previous
//
#include <hip/hip_runtime.h>
#include <hip/hip_bf16.h>

namespace {

constexpr int HD = 128;   // H
constexpr int SB = 1024;  // S
constexpr int BB = 1024;  // B

typedef __attribute__((ext_vector_type(4)))  float          f32x4;
typedef __attribute__((ext_vector_type(16))) float          f32x16;
typedef __attribute__((ext_vector_type(8)))  __bf16         bf16x8;
typedef __attribute__((ext_vector_type(8)))  unsigned short u16x8;
typedef __attribute__((ext_vector_type(4)))  unsigned short u16x4;

__device__ __forceinline__ float fast_tanh(float x) {
  float e = __expf(2.0f * x);
  return 1.0f - 2.0f * __builtin_amdgcn_rcpf(e + 1.0f);
}

} // namespace

// One block per batch row b. 8 waves. Wave w, chunk c computes scores for
// s in [c*256 + w*32, +32) over all 128 o's, via 32x32x16 bf16 MFMA with
// hi/lo split (3 products) for ~fp32 accuracy. Then block softmax over S.
//
// Register budget: measured R6/R10 — __launch_bounds__(512,{1,2}) both gave
// VGPR_Count=128 + ~64 AGPR (acc) + ~200MB/dispatch scratch spill, while
// occupancy stayed 1 block/CU (23%): the compiler spilled for a 4-waves/EU
// target the HW never achieved. Pin it: waves_per_eu(2,2) -> 256-reg
// budget/wave, ~200 live regs fit, no spill, same 1-block/CU residency.
extern "C" __global__
__attribute__((amdgpu_flat_work_group_size(512, 512), amdgpu_waves_per_eu(2, 2)))
void attn_fused(const float* __restrict__ hidden,
                const float* __restrict__ enc,
                const float* __restrict__ W,
                const float* __restrict__ bias,
                const float* __restrict__ vvec,
                float* __restrict__ out)
{
  __shared__ unsigned short WeHi[HD * HD];  // 32 KB, swizzled row-major bf16
  __shared__ unsigned short WeLo[HD * HD];  // 32 KB
  __shared__ float hid[HD];
  __shared__ float ehb[HD];                 // eh[b,o] + bias[o]
  __shared__ float sc[SB];                  // scores
  __shared__ float red[16];

  const int b    = blockIdx.x;
  const int tid  = threadIdx.x;
  const int lane = tid & 63;
  const int wv   = tid >> 6;   // wave 0..7
  const int l31  = lane & 31;
  const int hi   = lane >> 5;  // 0/1

  if (tid < 32)
    ((f32x4*)hid)[tid] = ((const f32x4*)(hidden + (size_t)b * HD))[tid];
  __syncthreads();

  if (tid < HD) {
    // ehb[o] = bias[o] + sum_h hidden[b,h] * W[o,h]   (Wh part, fp32)
    const float* wr = W + (size_t)tid * (2 * HD);
    float acc = bias[tid];
    #pragma unroll
    for (int h = 0; h < HD; h += 4) {
      f32x4 wq = *(const f32x4*)(wr + h);
      acc += hid[h]     * wq[0];
      acc += hid[h + 1] * wq[1];
      acc += hid[h + 2] * wq[2];
      acc += hid[h + 3] * wq[3];
    }
    ehb[tid] = acc;
  } else {
    // We[o,h] = W[o, 128+h] -> bf16 hi/lo into LDS, XOR-swizzled 16B granules
    for (int e = tid - HD; e < (HD * HD / 4); e += 384) {
      const int o  = e >> 5;
      const int h4 = (e & 31) << 2;
      f32x4 x = *(const f32x4*)(W + (size_t)o * (2 * HD) + HD + h4);
      const int g   = (h4 >> 3) ^ (o & 15);
      const int idx = o * HD + g * 8 + (h4 & 7);
      u16x4 hv, lv;
      #pragma unroll
      for (int j = 0; j < 4; ++j) {
        float xx = x[j];
        __bf16 hb = (__bf16)xx;
        float hf = (float)hb;
        __bf16 lb = (__bf16)(xx - hf);
        hv[j] = __builtin_bit_cast(unsigned short, hb);
        lv[j] = __builtin_bit_cast(unsigned short, lb);
      }
      *(u16x4*)&WeHi[idx] = hv;
      *(u16x4*)&WeLo[idx] = lv;
    }
  }
  __syncthreads();

  // per-lane o-constants: o = t*32 + l31 for 4 o-tiles
  const float vt0 = vvec[l31],      vt1 = vvec[32 + l31];
  const float vt2 = vvec[64 + l31], vt3 = vvec[96 + l31];
  const float et0 = ehb[l31],       et1 = ehb[32 + l31];
  const float et2 = ehb[64 + l31],  et3 = ehb[96 + l31];

  for (int c = 0; c < 4; ++c) {
    const int s0 = c * 256 + wv * 32;
    // A-fragment source: enc[b, s0+l31, k], k = ks*16 + hi*8 + 0..7
    const float* ap = enc + ((size_t)b * SB + (s0 + l31)) * HD + hi * 8;

    // preload the whole K=128 strip (8 frags of 8 f32) -> loads stay in flight
    f32x4 araw[16];
    #pragma unroll
    for (int ks = 0; ks < 8; ++ks) {
      araw[2 * ks]     = *(const f32x4*)(ap + ks * 16);
      araw[2 * ks + 1] = *(const f32x4*)(ap + ks * 16 + 4);
    }

    f32x16 acc0 = {}, acc1 = {}, acc2 = {}, acc3 = {};

    #pragma unroll
    for (int ks = 0; ks < 8; ++ks) {
      bf16x8 ah, al;
      #pragma unroll
      for (int j = 0; j < 8; ++j) {
        float xx = (j < 4) ? araw[2 * ks][j] : araw[2 * ks + 1][j - 4];
        __bf16 hb = (__bf16)xx;
        ah[j] = hb;
        al[j] = (__bf16)(xx - (float)hb);
      }
      const int gsw = ((ks * 2 + hi) ^ (l31 & 15)) * 8;

#define DO_TILE(ACC, T)                                                      \
      {                                                                      \
        const int bi = ((T) * 32 + l31) * HD + gsw;                          \
        bf16x8 bh = __builtin_bit_cast(bf16x8, *(const u16x8*)&WeHi[bi]);    \
        bf16x8 bl = __builtin_bit_cast(bf16x8, *(const u16x8*)&WeLo[bi]);    \
        ACC = __builtin_amdgcn_mfma_f32_32x32x16_bf16(ah, bh, ACC, 0, 0, 0); \
        ACC = __builtin_amdgcn_mfma_f32_32x32x16_bf16(al, bh, ACC, 0, 0, 0); \
        ACC = __builtin_amdgcn_mfma_f32_32x32x16_bf16(ah, bl, ACC, 0, 0, 0); \
      }

      DO_TILE(acc0, 0)
      DO_TILE(acc1, 1)
      DO_TILE(acc2, 2)
      DO_TILE(acc3, 3)
#undef DO_TILE
    }

    // epilogue: ps[r] = sum_o v[o]*tanh(ehb[o] + ee[s,o]); o = lane&31 per tile
    float ps[16];
    #pragma unroll
    for (int r = 0; r < 16; ++r) {
      ps[r] = vt0 * fast_tanh(acc0[r] + et0)
            + vt1 * fast_tanh(acc1[r] + et1)
            + vt2 * fast_tanh(acc2[r] + et2)
            + vt3 * fast_tanh(acc3[r] + et3);
    }
    // reduce over the 32 o-lanes (stays within each 32-lane half)
    #pragma unroll
    for (int d = 1; d <= 16; d <<= 1) {
      #pragma unroll
      for (int r = 0; r < 16; ++r)
        ps[r] += __shfl_xor(ps[r], d, 64);
    }
    if (l31 == 0) {
      #pragma unroll
      for (int r = 0; r < 16; ++r) {
        const int row = (r & 3) + 8 * (r >> 2) + 4 * hi;  // C/D row map
        sc[s0 + row] = ps[r];
      }
    }
  }
  __syncthreads();

  // ---- softmax over S = 1024 ----
  const float x0 = sc[tid];
  const float x1 = sc[tid + 512];
  float m = fmaxf(x0, x1);
  #pragma unroll
  for (int d = 32; d >= 1; d >>= 1) m = fmaxf(m, __shfl_xor(m, d, 64));
  if (lane == 0) red[wv] = m;
  __syncthreads();
  float M = red[0];
  #pragma unroll
  for (int i = 1; i < 8; ++i) M = fmaxf(M, red[i]);
  const float e0 = __expf(x0 - M);
  const float e1 = __expf(x1 - M);
  float s2 = e0 + e1;
  #pragma unroll
  for (int d = 32; d >= 1; d >>= 1) s2 += __shfl_xor(s2, d, 64);
  if (lane == 0) red[8 + wv] = s2;
  __syncthreads();
  float T = 0.0f;
  #pragma unroll
  for (int i = 0; i < 8; ++i) T += red[8 + i];
  const float inv = 1.0f / T;
  out[(size_t)b * SB + tid]       = e0 * inv;
  out[(size_t)b * SB + 512 + tid] = e1 * inv;
}

extern "C" void kernel_launch(void* const* d_in, const int* in_sizes, int n_in,
                              void* d_out, int out_size, void* d_ws, size_t ws_size,
                              hipStream_t stream) {
  const float* hidden = (const float*)d_in[0];
  const float* enc    = (const float*)d_in[1];
  const float* W      = (const float*)d_in[2];
  const float* bias   = (const float*)d_in[3];
  const float* vvec   = (const float*)d_in[4];
  float* out = (float*)d_out;
  (void)in_sizes; (void)n_in; (void)out_size; (void)d_ws; (void)ws_size;
  attn_fused<<<dim3(BB), dim3(512), 0, stream>>>(hidden, enc, W, bias, vvec, out);
}